// Round 2
// baseline (879.733 us; speedup 1.0000x reference)
//
#include <hip/hip_runtime.h>
#include <hip/hip_bf16.h>

#define VOCAB 8000
#define HIDDEN 256
#define BATCH 32
#define SEQ 256
#define NPAD 8064              // 63 * 128, zero-padded vocab for GEMM staging
#define MROWS (SEQ * BATCH)    // 65536

typedef __attribute__((ext_vector_type(8))) short short8;   // 8 bf16 (4 VGPRs)
typedef __attribute__((ext_vector_type(4))) short short4v;  // 4 bf16 (8B)
typedef __attribute__((ext_vector_type(4))) float floatx4;  // 4 f32 acc

// ---------- helpers ----------

__device__ __forceinline__ void async_copy16(const void* g, void* l) {
    __builtin_amdgcn_global_load_lds(
        (const __attribute__((address_space(1))) unsigned int*)g,
        (__attribute__((address_space(3))) unsigned int*)l, 16, 0, 0);
}

__device__ __forceinline__ unsigned short f32_to_bf16(float f) {
    unsigned int u = __float_as_uint(f);
    unsigned int lsb = (u >> 16) & 1u;
    u += 0x7fffu + lsb;            // round-to-nearest-even
    return (unsigned short)(u >> 16);
}

__device__ __forceinline__ float bf16_to_f32(unsigned short u) {
    return __uint_as_float(((unsigned int)u) << 16);
}

// ---------- kernel 1: W_out f32 -> bf16, zero-padded to NPAD rows ----------

__global__ void __launch_bounds__(256) convw_kernel(const float* __restrict__ W_out,
                                                    unsigned short* __restrict__ Wbf) {
    int v = blockIdx.x;           // 0..NPAD-1
    int k = threadIdx.x;          // 0..255
    float f = (v < VOCAB) ? W_out[(size_t)v * HIDDEN + k] : 0.0f;
    Wbf[(size_t)v * HIDDEN + k] = f32_to_bf16(f);
}

// ---------- kernel 2: embedding gather  xp[(s*32+b)*256+h] = W_ih[h, X[b,s]] + b_ih[h] ----------

__global__ void __launch_bounds__(256) gather_kernel(const int* __restrict__ X,
                                                     const float* __restrict__ W_ih,
                                                     const float* __restrict__ b_ih,
                                                     float* __restrict__ xp) {
    int n = blockIdx.x;           // n = s*BATCH + b, 0..8191
    int h = threadIdx.x;          // 0..255
    int s = n >> 5;
    int b = n & 31;
    int tok = X[b * SEQ + s];
    xp[(size_t)n * HIDDEN + h] = W_ih[(size_t)h * VOCAB + tok] + b_ih[h];
}

// ---------- kernel 3: Elman recurrence via MFMA ----------
// 2 blocks x 256 threads; block handles 16 batches. Per step compute
//   D[i][b] = x[b][i] + b_hh[i] + sum_k W_hh[i][k] * H[b][k]     (i=256, b=16, k=256)
// A-operand = W_hh, split bf16 hi/lo, STATIC in registers (64 frags/lane).
// B-operand = H^T, split bf16 hi/lo, double-buffered in LDS (row stride 264 shorts).
// 3-product bf16x3: Whi*Hhi + Wlo*Hhi + Whi*Hlo  -> ~f32 accuracy.
// C/D layout: row i_in_tile = lq*4+r (k-contiguous for next step's B!), col b = l16.

#define HSTR 264   // LDS row stride in shorts (pads 256 to break bank aliasing)

__global__ void __launch_bounds__(256, 1) rnn_kernel(const float* __restrict__ xp,
                                                     const float* __restrict__ h0,
                                                     const float* __restrict__ W_hh,
                                                     const float* __restrict__ b_hh,
                                                     unsigned short* __restrict__ Ybf,
                                                     float* __restrict__ h_last) {
    __shared__ __align__(16) unsigned short Hhi[2][16 * HSTR];
    __shared__ __align__(16) unsigned short Hlo[2][16 * HSTR];

    const int tid  = threadIdx.x;
    const int lane = tid & 63;
    const int wave = tid >> 6;       // 0..3 -> i-range [64*wave, 64*wave+64)
    const int l16  = lane & 15;      // A: i row-in-tile; B: batch col; C: batch col
    const int lq   = lane >> 4;      // 0..3
    const int bg0  = blockIdx.x * 16;

    // ---- load + split W_hh A-fragments: Whi/Wlo[t][c] ----
    // lane holds W_hh[i = 64*wave + 16t + l16][k = 32c + 8*lq .. +8]
    short8 Whi[4][8], Wlo[4][8];
#pragma unroll
    for (int t = 0; t < 4; ++t) {
#pragma unroll
        for (int c = 0; c < 8; ++c) {
            const float* p = W_hh + (size_t)(64 * wave + 16 * t + l16) * HIDDEN + 32 * c + 8 * lq;
            float4 f0 = *(const float4*)p;
            float4 f1 = *(const float4*)(p + 4);
            float v[8] = {f0.x, f0.y, f0.z, f0.w, f1.x, f1.y, f1.z, f1.w};
            short8 hi, lo;
#pragma unroll
            for (int e = 0; e < 8; ++e) {
                unsigned short h16 = f32_to_bf16(v[e]);
                hi[e] = (short)h16;
                lo[e] = (short)f32_to_bf16(v[e] - bf16_to_f32(h16));
            }
            Whi[t][c] = hi;
            Wlo[t][c] = lo;
        }
    }

    float4 bhh[4];   // b_hh[i], i = 64*wave + 16t + 4*lq + r
#pragma unroll
    for (int t = 0; t < 4; ++t)
        bhh[t] = *(const float4*)(b_hh + 64 * wave + 16 * t + 4 * lq);

    // ---- init H buffer 0 from h0 (hi/lo split) ----
    {
        int b  = tid >> 4;           // 0..15
        int k0 = (tid & 15) * 16;    // 16 consecutive k
#pragma unroll
        for (int k = 0; k < 16; ++k) {
            float h = h0[(size_t)(bg0 + b) * HIDDEN + k0 + k];
            unsigned short hh = f32_to_bf16(h);
            Hhi[0][b * HSTR + k0 + k] = hh;
            Hlo[0][b * HSTR + k0 + k] = f32_to_bf16(h - bf16_to_f32(hh));
        }
    }

    // prefetch x for step 0: x[b = l16][i = 64*wave + 16t + 4*lq + r]
    float4 xbuf[4];
#pragma unroll
    for (int t = 0; t < 4; ++t)
        xbuf[t] = *(const float4*)(xp + (size_t)(bg0 + l16) * HIDDEN + 64 * wave + 16 * t + 4 * lq);

    __syncthreads();

    for (int s = 0; s < SEQ; ++s) {
        const int cur = s & 1, nxt = cur ^ 1;

        floatx4 acc[4];
#pragma unroll
        for (int t = 0; t < 4; ++t) {
            acc[t][0] = xbuf[t].x + bhh[t].x;
            acc[t][1] = xbuf[t].y + bhh[t].y;
            acc[t][2] = xbuf[t].z + bhh[t].z;
            acc[t][3] = xbuf[t].w + bhh[t].w;
        }

        // prefetch x for step s+1 (hidden under the MFMA chain)
        if (s + 1 < SEQ) {
#pragma unroll
            for (int t = 0; t < 4; ++t)
                xbuf[t] = *(const float4*)(xp + (size_t)((s + 1) * BATCH + bg0 + l16) * HIDDEN +
                                           64 * wave + 16 * t + 4 * lq);
        }

        // K accumulation: 8 chunks x 4 tiles x 3 products = 96 MFMAs
#pragma unroll
        for (int c = 0; c < 8; ++c) {
            short8 bhi = *(const short8*)&Hhi[cur][l16 * HSTR + 32 * c + 8 * lq];
            short8 blo = *(const short8*)&Hlo[cur][l16 * HSTR + 32 * c + 8 * lq];
#pragma unroll
            for (int t = 0; t < 4; ++t) {
                acc[t] = __builtin_amdgcn_mfma_f32_16x16x32_bf16(Whi[t][c], bhi, acc[t], 0, 0, 0);
                acc[t] = __builtin_amdgcn_mfma_f32_16x16x32_bf16(Wlo[t][c], bhi, acc[t], 0, 0, 0);
                acc[t] = __builtin_amdgcn_mfma_f32_16x16x32_bf16(Whi[t][c], blo, acc[t], 0, 0, 0);
            }
        }

        // epilogue: tanh, split hi/lo, write H[nxt] + Y
#pragma unroll
        for (int t = 0; t < 4; ++t) {
            const int i0 = 64 * wave + 16 * t + 4 * lq;   // 4 consecutive i = next-step k
            float hn[4];
            short4v hi4, lo4;
#pragma unroll
            for (int r = 0; r < 4; ++r) {
                // tanh(a) = 1 - 2/(exp(2a)+1), exp via exp2
                float e  = __builtin_amdgcn_exp2f(acc[t][r] * 2.88539004f);
                float rc = __builtin_amdgcn_rcpf(e + 1.0f);
                hn[r] = fmaf(-2.0f, rc, 1.0f);
                unsigned short hh = f32_to_bf16(hn[r]);
                hi4[r] = (short)hh;
                lo4[r] = (short)f32_to_bf16(hn[r] - bf16_to_f32(hh));
            }
            *(short4v*)&Hhi[nxt][l16 * HSTR + i0] = hi4;
            *(short4v*)&Hlo[nxt][l16 * HSTR + i0] = lo4;
            *(short4v*)(Ybf + (size_t)(s * BATCH + bg0 + l16) * HIDDEN + i0) = hi4;
            if (s == SEQ - 1) {
#pragma unroll
                for (int r = 0; r < 4; ++r)
                    h_last[(size_t)(bg0 + l16) * HIDDEN + i0 + r] = hn[r];
            }
        }
        __syncthreads();   // one barrier/step: H double-buffered
    }
}

// ---------- kernel 4: out = Y(bf16) @ Wout(bf16)^T + b_out  (M=65536, N=8000, K=256) ----------
// 128x128 tile, BK=32, 4 waves (2x2), each wave 64x64 via 4x4 MFMA 16x16x32 tiles.

__global__ void __launch_bounds__(256) gemm_kernel(const unsigned short* __restrict__ Ybf,
                                                   const unsigned short* __restrict__ Wbf,
                                                   const float* __restrict__ b_out,
                                                   float* __restrict__ out) {
    __shared__ __align__(16) short sA[128 * 32];
    __shared__ __align__(16) short sB[128 * 32];

    const int tid  = threadIdx.x;
    const int lane = tid & 63;
    const int wave = tid >> 6;
    const int wm   = wave >> 1;
    const int wn   = wave & 1;
    const int l16  = lane & 15;
    const int lq   = lane >> 4;

    const int m0 = blockIdx.y * 128;
    const int n0 = blockIdx.x * 128;

    floatx4 acc[4][4] = {};

    const int chunk0 = tid;
    const int chunk1 = 256 + tid;
    const int rowA0 = chunk0 >> 2, kc0 = chunk0 & 3;
    const int rowA1 = chunk1 >> 2, kc1 = chunk1 & 3;

    for (int k0 = 0; k0 < HIDDEN; k0 += 32) {
        async_copy16(Ybf + (size_t)(m0 + rowA0) * HIDDEN + k0 + kc0 * 8, sA + chunk0 * 8);
        async_copy16(Ybf + (size_t)(m0 + rowA1) * HIDDEN + k0 + kc1 * 8, sA + chunk1 * 8);
        async_copy16(Wbf + (size_t)(n0 + rowA0) * HIDDEN + k0 + kc0 * 8, sB + chunk0 * 8);
        async_copy16(Wbf + (size_t)(n0 + rowA1) * HIDDEN + k0 + kc1 * 8, sB + chunk1 * 8);
        __syncthreads();

        short8 afrag[4], bfrag[4];
#pragma unroll
        for (int t = 0; t < 4; ++t) {
            afrag[t] = *(const short8*)&sA[(wm * 64 + t * 16 + l16) * 32 + lq * 8];
            bfrag[t] = *(const short8*)&sB[(wn * 64 + t * 16 + l16) * 32 + lq * 8];
        }
#pragma unroll
        for (int tm = 0; tm < 4; ++tm)
#pragma unroll
            for (int tn = 0; tn < 4; ++tn)
                acc[tm][tn] = __builtin_amdgcn_mfma_f32_16x16x32_bf16(
                    afrag[tm], bfrag[tn], acc[tm][tn], 0, 0, 0);
        __syncthreads();
    }

#pragma unroll
    for (int tn = 0; tn < 4; ++tn) {
        int n = n0 + wn * 64 + tn * 16 + l16;
        if (n < VOCAB) {
            float bo = b_out[n];
#pragma unroll
            for (int tm = 0; tm < 4; ++tm) {
                int mbase = m0 + wm * 64 + tm * 16 + lq * 4;
#pragma unroll
                for (int r = 0; r < 4; ++r) {
                    out[(size_t)(mbase + r) * VOCAB + n] = acc[tm][tn][r] + bo;
                }
            }
        }
    }
}

// ---------- launch ----------

extern "C" void kernel_launch(void* const* d_in, const int* in_sizes, int n_in,
                              void* d_out, int out_size, void* d_ws, size_t ws_size,
                              hipStream_t stream) {
    const int*   X     = (const int*)d_in[0];
    const float* h0    = (const float*)d_in[1];
    const float* W_ih  = (const float*)d_in[2];
    const float* b_ih  = (const float*)d_in[3];
    const float* W_hh  = (const float*)d_in[4];
    const float* b_hh  = (const float*)d_in[5];
    const float* W_out = (const float*)d_in[6];
    const float* b_out = (const float*)d_in[7];

    float* out    = (float*)d_out;
    float* h_last = out + (size_t)MROWS * VOCAB;

    char* ws = (char*)d_ws;
    float*          xp  = (float*)ws;                          //  8,388,608 B
    unsigned short* Ybf = (unsigned short*)(ws + 8388608);     // 33,554,432 B
    unsigned short* Wbf = (unsigned short*)(ws + 41943040);    //  4,128,768 B

    hipLaunchKernelGGL(convw_kernel,  dim3(NPAD),        dim3(256), 0, stream, W_out, Wbf);
    hipLaunchKernelGGL(gather_kernel, dim3(SEQ * BATCH), dim3(256), 0, stream, X, W_ih, b_ih, xp);
    hipLaunchKernelGGL(rnn_kernel,    dim3(2),           dim3(256), 0, stream,
                       xp, h0, W_hh, b_hh, Ybf, h_last);
    hipLaunchKernelGGL(gemm_kernel,   dim3(NPAD / 128, MROWS / 128), dim3(256), 0, stream,
                       Ybf, Wbf, b_out, out);
}

// Round 3
// 634.014 us; speedup vs baseline: 1.3876x; 1.3876x over previous
//
#include <hip/hip_runtime.h>
#include <hip/hip_bf16.h>

#define VOCAB 8000
#define HIDDEN 256
#define BATCH 32
#define SEQ 256
#define NPAD 8064              // 63 * 128, zero-padded vocab for GEMM staging
#define MROWS (SEQ * BATCH)    // 65536

typedef __attribute__((ext_vector_type(8))) short short8;   // 8 bf16 (4 VGPRs)
typedef __attribute__((ext_vector_type(4))) short short4v;  // 4 bf16 (8B)
typedef __attribute__((ext_vector_type(4))) float floatx4;  // 4 f32 acc

// ---------- helpers ----------

__device__ __forceinline__ void async_copy16(const void* g, void* l) {
    __builtin_amdgcn_global_load_lds(
        (const __attribute__((address_space(1))) unsigned int*)g,
        (__attribute__((address_space(3))) unsigned int*)l, 16, 0, 0);
}

__device__ __forceinline__ unsigned short f32_to_bf16(float f) {
    unsigned int u = __float_as_uint(f);
    unsigned int lsb = (u >> 16) & 1u;
    u += 0x7fffu + lsb;            // round-to-nearest-even
    return (unsigned short)(u >> 16);
}

__device__ __forceinline__ float bf16_to_f32(unsigned short u) {
    return __uint_as_float(((unsigned int)u) << 16);
}

// ---------- kernel 1: W_out f32 -> bf16, zero-padded to NPAD rows ----------

__global__ void __launch_bounds__(256) convw_kernel(const float* __restrict__ W_out,
                                                    unsigned short* __restrict__ Wbf) {
    int v = blockIdx.x;           // 0..NPAD-1
    int k = threadIdx.x;          // 0..255
    float f = (v < VOCAB) ? W_out[(size_t)v * HIDDEN + k] : 0.0f;
    Wbf[(size_t)v * HIDDEN + k] = f32_to_bf16(f);
}

// ---------- kernel 2: embedding gather  xp[(s*32+b)*256+h] = W_ih[h, X[b,s]] + b_ih[h] ----------

__global__ void __launch_bounds__(256) gather_kernel(const int* __restrict__ X,
                                                     const float* __restrict__ W_ih,
                                                     const float* __restrict__ b_ih,
                                                     float* __restrict__ xp) {
    int n = blockIdx.x;           // n = s*BATCH + b, 0..8191
    int h = threadIdx.x;          // 0..255
    int s = n >> 5;
    int b = n & 31;
    int tok = X[b * SEQ + s];
    xp[(size_t)n * HIDDEN + h] = W_ih[(size_t)h * VOCAB + tok] + b_ih[h];
}

// ---------- kernel 3: Elman recurrence via MFMA (v3) ----------
// 2 blocks x 512 threads (8 waves = 2/SIMD); block handles 16 batches.
// Per step: D[i][b] = x[b][i] + b_hh[i] + sum_k W_hh[i][k]*H[b][k]  (i=256,b=16,k=256)
// Wave w owns i-range [32w, 32w+32) = 2 MFMA i-tiles.
// A = W_hh split bf16 hi/lo, STATIC in regs (32 short8 = 128 VGPRs/lane).
// B = H^T single bf16, double-buffered LDS.  bf16x2: Whi*H + Wlo*H (W exact to 2^-17).
// Separate hi/lo accumulators -> 4 independent 8-deep MFMA chains.
// C/D layout (verified R2): col b = lane&15, row i-in-tile = (lane>>4)*4 + reg.

#define HSTR 264   // LDS row stride in shorts

__global__ void __launch_bounds__(512, 2) rnn_kernel(const float* __restrict__ xp,
                                                     const float* __restrict__ h0,
                                                     const float* __restrict__ W_hh,
                                                     const float* __restrict__ b_hh,
                                                     unsigned short* __restrict__ Ybf,
                                                     float* __restrict__ h_last) {
    __shared__ __align__(16) unsigned short Hh[2][16 * HSTR];

    const int tid  = threadIdx.x;
    const int lane = tid & 63;
    const int w    = tid >> 6;       // wave 0..7 -> i-range [32w, 32w+32)
    const int l16  = lane & 15;      // A: i row-in-tile; B/C: batch col
    const int lq   = lane >> 4;      // 0..3
    const int bg0  = blockIdx.x * 16;

    // ---- load + split W_hh A-fragments ----
    // lane holds W_hh[i = 32w + 16t + l16][k = 32c + 8lq .. +8]
    short8 Whi[2][8], Wlo[2][8];
#pragma unroll
    for (int t = 0; t < 2; ++t) {
#pragma unroll
        for (int c = 0; c < 8; ++c) {
            const float* p = W_hh + (size_t)(32 * w + 16 * t + l16) * HIDDEN + 32 * c + 8 * lq;
            float4 f0 = *(const float4*)p;
            float4 f1 = *(const float4*)(p + 4);
            float v[8] = {f0.x, f0.y, f0.z, f0.w, f1.x, f1.y, f1.z, f1.w};
            short8 hi, lo;
#pragma unroll
            for (int e = 0; e < 8; ++e) {
                unsigned short h16 = f32_to_bf16(v[e]);
                hi[e] = (short)h16;
                lo[e] = (short)f32_to_bf16(v[e] - bf16_to_f32(h16));
            }
            Whi[t][c] = hi;
            Wlo[t][c] = lo;
        }
    }

    float4 bhh[2];   // b_hh[i], i = 32w + 16t + 4lq + r
#pragma unroll
    for (int t = 0; t < 2; ++t)
        bhh[t] = *(const float4*)(b_hh + 32 * w + 16 * t + 4 * lq);

    // ---- init H buffer 0 from h0 ----
    {
        int b  = tid >> 5;            // 0..15
        int k0 = (tid & 31) * 8;      // 8 consecutive k
#pragma unroll
        for (int k = 0; k < 8; ++k)
            Hh[0][b * HSTR + k0 + k] = f32_to_bf16(h0[(size_t)(bg0 + b) * HIDDEN + k0 + k]);
    }

    // prefetch x for step 0: x[b = l16][i = 32w + 16t + 4lq + r]
    float4 xbuf[2];
#pragma unroll
    for (int t = 0; t < 2; ++t)
        xbuf[t] = *(const float4*)(xp + (size_t)(bg0 + l16) * HIDDEN + 32 * w + 16 * t + 4 * lq);

    __syncthreads();

#pragma unroll 1
    for (int s = 0; s < SEQ; ++s) {
        const unsigned short* Hc = Hh[s & 1];
        unsigned short*       Hn = Hh[(s & 1) ^ 1];

        // all 8 B-frags up front (8 x ds_read_b128, compiler staggers lgkmcnt)
        short8 hb[8];
#pragma unroll
        for (int c = 0; c < 8; ++c)
            hb[c] = *(const short8*)&Hc[l16 * HSTR + 32 * c + 8 * lq];

        floatx4 a1[2], a2[2];
#pragma unroll
        for (int t = 0; t < 2; ++t) {
            a1[t][0] = xbuf[t].x + bhh[t].x;
            a1[t][1] = xbuf[t].y + bhh[t].y;
            a1[t][2] = xbuf[t].z + bhh[t].z;
            a1[t][3] = xbuf[t].w + bhh[t].w;
            a2[t][0] = a2[t][1] = a2[t][2] = a2[t][3] = 0.f;
        }

        // prefetch next x (independent global loads, hidden under MFMAs)
        if (s + 1 < SEQ) {
#pragma unroll
            for (int t = 0; t < 2; ++t)
                xbuf[t] = *(const float4*)(xp + (size_t)((s + 1) * BATCH + bg0 + l16) * HIDDEN +
                                           32 * w + 16 * t + 4 * lq);
        }

        // 32 MFMAs: 4 independent chains (a1[0], a1[1], a2[0], a2[1]), 8 deep each
#pragma unroll
        for (int c = 0; c < 8; ++c) {
            a1[0] = __builtin_amdgcn_mfma_f32_16x16x32_bf16(Whi[0][c], hb[c], a1[0], 0, 0, 0);
            a1[1] = __builtin_amdgcn_mfma_f32_16x16x32_bf16(Whi[1][c], hb[c], a1[1], 0, 0, 0);
            a2[0] = __builtin_amdgcn_mfma_f32_16x16x32_bf16(Wlo[0][c], hb[c], a2[0], 0, 0, 0);
            a2[1] = __builtin_amdgcn_mfma_f32_16x16x32_bf16(Wlo[1][c], hb[c], a2[1], 0, 0, 0);
        }

        // epilogue: tanh, pack bf16, write H[next] + Y
#pragma unroll
        for (int t = 0; t < 2; ++t) {
            const int i0 = 32 * w + 16 * t + 4 * lq;   // 4 consecutive i = next-step k
            float hn[4];
            short4v hi4;
#pragma unroll
            for (int r = 0; r < 4; ++r) {
                float a  = a1[t][r] + a2[t][r];
                // tanh(a) = 1 - 2/(exp(2a)+1)
                float e  = __builtin_amdgcn_exp2f(a * 2.88539004f);
                float rc = __builtin_amdgcn_rcpf(e + 1.0f);
                hn[r] = fmaf(-2.0f, rc, 1.0f);
                hi4[r] = (short)f32_to_bf16(hn[r]);
            }
            *(short4v*)&Hn[l16 * HSTR + i0] = hi4;
            *(short4v*)(Ybf + (size_t)(s * BATCH + bg0 + l16) * HIDDEN + i0) = hi4;
            if (s == SEQ - 1) {
#pragma unroll
                for (int r = 0; r < 4; ++r)
                    h_last[(size_t)(bg0 + l16) * HIDDEN + i0 + r] = hn[r];
            }
        }
        __syncthreads();   // one barrier/step (H double-buffered)
    }
}

// ---------- kernel 4: out = Y(bf16) @ Wout(bf16)^T + b_out  (M=65536, N=8000, K=256) ----------
// 128x128 tile, BK=32, 4 waves (2x2), each wave 64x64 via 4x4 MFMA 16x16x32 tiles.

__global__ void __launch_bounds__(256) gemm_kernel(const unsigned short* __restrict__ Ybf,
                                                   const unsigned short* __restrict__ Wbf,
                                                   const float* __restrict__ b_out,
                                                   float* __restrict__ out) {
    __shared__ __align__(16) short sA[128 * 32];
    __shared__ __align__(16) short sB[128 * 32];

    const int tid  = threadIdx.x;
    const int lane = tid & 63;
    const int wave = tid >> 6;
    const int wm   = wave >> 1;
    const int wn   = wave & 1;
    const int l16  = lane & 15;
    const int lq   = lane >> 4;

    const int m0 = blockIdx.y * 128;
    const int n0 = blockIdx.x * 128;

    floatx4 acc[4][4] = {};

    const int chunk0 = tid;
    const int chunk1 = 256 + tid;
    const int rowA0 = chunk0 >> 2, kc0 = chunk0 & 3;
    const int rowA1 = chunk1 >> 2, kc1 = chunk1 & 3;

    for (int k0 = 0; k0 < HIDDEN; k0 += 32) {
        async_copy16(Ybf + (size_t)(m0 + rowA0) * HIDDEN + k0 + kc0 * 8, sA + chunk0 * 8);
        async_copy16(Ybf + (size_t)(m0 + rowA1) * HIDDEN + k0 + kc1 * 8, sA + chunk1 * 8);
        async_copy16(Wbf + (size_t)(n0 + rowA0) * HIDDEN + k0 + kc0 * 8, sB + chunk0 * 8);
        async_copy16(Wbf + (size_t)(n0 + rowA1) * HIDDEN + k0 + kc1 * 8, sB + chunk1 * 8);
        __syncthreads();

        short8 afrag[4], bfrag[4];
#pragma unroll
        for (int t = 0; t < 4; ++t) {
            afrag[t] = *(const short8*)&sA[(wm * 64 + t * 16 + l16) * 32 + lq * 8];
            bfrag[t] = *(const short8*)&sB[(wn * 64 + t * 16 + l16) * 32 + lq * 8];
        }
#pragma unroll
        for (int tm = 0; tm < 4; ++tm)
#pragma unroll
            for (int tn = 0; tn < 4; ++tn)
                acc[tm][tn] = __builtin_amdgcn_mfma_f32_16x16x32_bf16(
                    afrag[tm], bfrag[tn], acc[tm][tn], 0, 0, 0);
        __syncthreads();
    }

#pragma unroll
    for (int tn = 0; tn < 4; ++tn) {
        int n = n0 + wn * 64 + tn * 16 + l16;
        if (n < VOCAB) {
            float bo = b_out[n];
#pragma unroll
            for (int tm = 0; tm < 4; ++tm) {
                int mbase = m0 + wm * 64 + tm * 16 + lq * 4;
#pragma unroll
                for (int r = 0; r < 4; ++r) {
                    out[(size_t)(mbase + r) * VOCAB + n] = acc[tm][tn][r] + bo;
                }
            }
        }
    }
}

// ---------- launch ----------

extern "C" void kernel_launch(void* const* d_in, const int* in_sizes, int n_in,
                              void* d_out, int out_size, void* d_ws, size_t ws_size,
                              hipStream_t stream) {
    const int*   X     = (const int*)d_in[0];
    const float* h0    = (const float*)d_in[1];
    const float* W_ih  = (const float*)d_in[2];
    const float* b_ih  = (const float*)d_in[3];
    const float* W_hh  = (const float*)d_in[4];
    const float* b_hh  = (const float*)d_in[5];
    const float* W_out = (const float*)d_in[6];
    const float* b_out = (const float*)d_in[7];

    float* out    = (float*)d_out;
    float* h_last = out + (size_t)MROWS * VOCAB;

    char* ws = (char*)d_ws;
    float*          xp  = (float*)ws;                          //  8,388,608 B
    unsigned short* Ybf = (unsigned short*)(ws + 8388608);     // 33,554,432 B
    unsigned short* Wbf = (unsigned short*)(ws + 41943040);    //  4,128,768 B

    hipLaunchKernelGGL(convw_kernel,  dim3(NPAD),        dim3(256), 0, stream, W_out, Wbf);
    hipLaunchKernelGGL(gather_kernel, dim3(SEQ * BATCH), dim3(256), 0, stream, X, W_ih, b_ih, xp);
    hipLaunchKernelGGL(rnn_kernel,    dim3(2),           dim3(512), 0, stream,
                       xp, h0, W_hh, b_hh, Ybf, h_last);
    hipLaunchKernelGGL(gemm_kernel,   dim3(NPAD / 128, MROWS / 128), dim3(256), 0, stream,
                       Ybf, Wbf, b_out, out);
}